// Round 4
// baseline (115.370 us; speedup 1.0000x reference)
//
#include <hip/hip_runtime.h>

#define B_ 2
#define N_ 512
#define C_ 128   // HIDDEN_DIM
#define A_ 64    // ATTN_DIM
#define H_ 128
#define TI 2     // query rows per attn block

#define SC2L 2.885390081777927f   // 2*log2(e)
#define LG2E 1.4426950408889634f  // log2(e)

// workspace layout (float offsets)
#define OFF_WET 0                           // We^T [A][H]
#define OFF_TO  (OFF_WET + A_*H_)           // tanh(h_o) [g][a]
#define OFF_T1S (OFF_TO + B_*N_*A_)         // tanh(h_1) [g][a]
#define OFF_T1T (OFF_T1S + B_*N_*A_)        // tanh(h_1) [b][a][n]
#define OFF_XY  (OFF_T1T + B_*N_*A_)        // Xy [g][h]

__device__ __forceinline__ float fexp2(float x) { return __builtin_amdgcn_exp2f(x); }
__device__ __forceinline__ float frcp(float x)  { return __builtin_amdgcn_rcpf(x); }
__device__ __forceinline__ float ftanh(float x) {
  return 1.0f - 2.0f * frcp(fexp2(SC2L * x) + 1.0f);
}

// ---------------- kernel 1: projections + tanh (reads raw weights) ----------
// 512 blocks x 512 threads; thread = (rsub, col): 2 rows, 256 cols per block.
// cols 0..63 -> tanh(h_o); 64..127 -> tanh(h_1) (+transposed copy); 128..255 -> Xy.
__global__ __launch_bounds__(512) void proj_kernel(
    const float* __restrict__ X, const float* __restrict__ Wo,
    const float* __restrict__ W1, const float* __restrict__ Wy,
    const float* __restrict__ by, const float* __restrict__ We,
    float* __restrict__ ws) {
  __shared__ float xs[2][C_];
  int row0 = blockIdx.x * 2;
  int t = threadIdx.x;
  if (t < 2*C_) xs[t >> 7][t & 127] = X[(size_t)row0*C_ + t];
  __syncthreads();

  int rsub = t >> 8;        // 0/1
  int col  = t & 255;
  int g = row0 + rsub;

  const float* W;
  if (col < 64)       W = Wo + (size_t)col*C_;
  else if (col < 128) W = W1 + (size_t)(col - 64)*C_;
  else                W = Wy + (size_t)(col - 128)*C_;

  const float4* w4 = (const float4*)W;
  const float4* x4 = (const float4*)xs[rsub];
  float acc = 0.f;
  #pragma unroll 8
  for (int k = 0; k < C_/4; ++k) {
    float4 wv = w4[k];
    float4 xv = x4[k];
    acc = fmaf(wv.x, xv.x, acc);
    acc = fmaf(wv.y, xv.y, acc);
    acc = fmaf(wv.z, xv.z, acc);
    acc = fmaf(wv.w, xv.w, acc);
  }

  if (col < 64) {
    ws[OFF_TO + (size_t)g*A_ + col] = ftanh(acc);
  } else if (col < 128) {
    int a = col - 64;
    float tv = ftanh(acc);
    ws[OFF_T1S + (size_t)g*A_ + a] = tv;
    int b = g >> 9, n = g & (N_-1);
    ws[OFF_T1T + (size_t)b*A_*N_ + (size_t)a*N_ + n] = tv;
  } else {
    int h = col - 128;
    ws[OFF_XY + (size_t)g*H_ + h] = acc + by[h];
  }

  // block 0 additionally transposes We [H][A] -> wet [A][H]
  if (blockIdx.x == 0) {
    for (int k = t; k < A_*H_; k += 512) {
      int h = k >> 6, a = k & 63;
      ws[OFF_WET + a*H_ + h] = We[k];
    }
  }
}

// ---------------- kernel 2: attention main ----------------
// 512 blocks x 1024 threads (16 waves), TI=2 rows/block, 2 blocks/CU (100% occ).
// tanh(ho+h1) = (to+tb)*rcp(1+to*tb); softmax without max-shift (|s| < 4).
__global__ __launch_bounds__(1024, 8) void attn_kernel(
    const float* __restrict__ Wphi, const float* __restrict__ be,
    const float* __restrict__ ws, float* __restrict__ out) {
  __shared__ float sc[TI][N_];        // unnormalized softmax p       (4 KB)
  __shared__ float reds[TI][8];       // per-wave denom partials
  __shared__ float4 pk[TI][A_];       // {to, wph*to, wph, 0}         (2 KB)
  __shared__ float ebw[TI][8][A_];    // per-wave ebar partials       (4 KB)
  __shared__ float ebar[TI][A_];      // unnormalized ebar
  __shared__ float p1s[TI][8][H_];    // part1 partials per j-octant  (8 KB)

  int t = threadIdx.x;
  int w = t >> 6, lane = t & 63;
  int blk = blockIdx.x;               // 0..511
  int b = blk >> 8;
  int i0 = (blk & 255) * TI;

  const float* tog = ws + OFF_TO  + (size_t)(b*N_ + i0)*A_;
  const float* t1s = ws + OFF_T1S + (size_t)(b*N_)*A_;
  const float* t1t = ws + OFF_T1T + (size_t)b*A_*N_;
  const float* xyg = ws + OFF_XY  + (size_t)(b*N_)*H_;
  const float* wet = ws + OFF_WET;

  if (t < TI*A_) {
    int r = t >> 6, a = t & 63;
    float to = tog[r*A_ + a];
    float wv = Wphi[a];
    pk[r][a] = make_float4(to, wv*to, wv, 0.f);
  }
  __syncthreads();

  // ---- Pass A: thread owns (r = t>>9, j = t&511)
  {
    int r = t >> 9, j = t & 511;
    const float* t1p = t1t + j;
    const float4* pkr = pk[r];
    float s = 0.f;
    #pragma unroll 4
    for (int a = 0; a < A_; ++a) {
      float tb = t1p[(size_t)a*N_];
      float4 k = pkr[a];
      float den = fmaf(k.x, tb, 1.0f);       // 1 + to*tb
      float num = fmaf(k.z, tb, k.y);        // wph*tb + wph*to
      s = fmaf(num, frcp(den), s);
    }
    float p = fexp2(LG2E * s);               // no max-shift: |s| < 4
    float q = p;
    #pragma unroll
    for (int m = 1; m < 64; m <<= 1) q += __shfl_xor(q, m);
    sc[r][j] = p;
    if (lane == 0) reds[r][w & 7] = q;
  }
  __syncthreads();

  // ---- Pass C: lane = a; wave (r = w>>3, wi = w&7) covers j = jj*8+wi
  {
    int r = w >> 3, wi = w & 7;
    float to = pk[r][lane].x;
    float c = 0.f;
    #pragma unroll 4
    for (int jj = 0; jj < N_/8; ++jj) {
      int j = jj*8 + wi;
      float tb = t1s[(size_t)j*A_ + lane];
      float pj = sc[r][j];
      float den = fmaf(to, tb, 1.0f);
      float num = to + tb;
      c = fmaf(pj*num, frcp(den), c);
    }
    ebw[r][wi][lane] = c;
  }

  // ---- part1: thread = (oct = t>>7, h = t&127); both rows share xv load
  {
    int h = t & 127, oct = t >> 7;
    const float* xq = xyg + (size_t)(oct*64)*H_ + h;
    float d0 = 0.f, d1 = 0.f;
    #pragma unroll 4
    for (int jc = 0; jc < 64; ++jc) {
      int j = oct*64 + jc;
      float xv = xq[(size_t)jc*H_];
      d0 = fmaf(sc[0][j], xv, d0);
      d1 = fmaf(sc[1][j], xv, d1);
    }
    p1s[0][oct][h] = d0;
    p1s[1][oct][h] = d1;
  }
  __syncthreads();

  // ---- combine ebar partials
  if (t < TI*A_) {
    int r = t >> 6, a = t & 63;
    float e = 0.f;
    #pragma unroll
    for (int k = 0; k < 8; ++k) e += ebw[r][k][a];
    ebar[r][a] = e;
  }
  __syncthreads();

  // ---- epilogue: out = (part1_un + We·ebar_un)·(1/l) + be
  if (t < TI*H_) {
    int h = t & 127, r = t >> 7;
    float acc = 0.f;
    #pragma unroll
    for (int o = 0; o < 8; ++o) acc += p1s[r][o][h];
    float e2 = 0.f;
    #pragma unroll 8
    for (int a = 0; a < A_; ++a) e2 = fmaf(ebar[r][a], wet[a*H_ + h], e2);
    float l = 0.f;
    #pragma unroll
    for (int k = 0; k < 8; ++k) l += reds[r][k];
    out[(size_t)(b*N_ + i0 + r)*H_ + h] = (acc + e2) * frcp(l) + be[h];
  }
}

extern "C" void kernel_launch(void* const* d_in, const int* in_sizes, int n_in,
                              void* d_out, int out_size, void* d_ws, size_t ws_size,
                              hipStream_t stream) {
  const float* X    = (const float*)d_in[0];
  const float* Wo   = (const float*)d_in[1];
  const float* W1   = (const float*)d_in[2];
  const float* Wphi = (const float*)d_in[3];
  const float* Wy   = (const float*)d_in[4];
  const float* by   = (const float*)d_in[5];
  const float* We   = (const float*)d_in[6];
  const float* be   = (const float*)d_in[7];
  float* out = (float*)d_out;
  float* ws  = (float*)d_ws;

  hipLaunchKernelGGL(proj_kernel, dim3(B_*N_/2), dim3(512), 0, stream,
                     X, Wo, W1, Wy, by, We, ws);
  hipLaunchKernelGGL(attn_kernel, dim3(B_*N_/TI), dim3(1024), 0, stream,
                     Wphi, be, ws, out);
}

// Round 5
// 108.516 us; speedup vs baseline: 1.0632x; 1.0632x over previous
//
#include <hip/hip_runtime.h>

#define B_ 2
#define N_ 512
#define C_ 128   // HIDDEN_DIM
#define A_ 64    // ATTN_DIM
#define H_ 128
#define TI 2     // query rows per attn block

#define SC2L 2.885390081777927f     // 2*log2(e): exp(2x)=2^(SC2L*x)
#define NEG2LE -2.885390081777927f  // -2*log2(e): exp(-2s)=2^(NEG2LE*s)

// workspace layout (float offsets)
#define OFF_WET 0                           // We^T [A][H]
#define OFF_V   (OFF_WET + A_*H_)           // v = exp(2*h_o) [g][a]
#define OFF_US  (OFF_V  + B_*N_*A_)         // u = exp(2*h_1) [g][a]
#define OFF_UQ  (OFF_US + B_*N_*A_)         // u quad [b][a>>2][n][a&3]
#define OFF_XY  (OFF_UQ + B_*N_*A_)         // Xy [g][h]

__device__ __forceinline__ float fexp2(float x) { return __builtin_amdgcn_exp2f(x); }
__device__ __forceinline__ float frcp(float x)  { return __builtin_amdgcn_rcpf(x); }

// ---------------- kernel 1: projections -> u, v, Xy ----------------
// 512 blocks x 512 threads; thread = (rsub = t>>8, col = t&255), 2 rows/block.
__global__ __launch_bounds__(512) void proj_kernel(
    const float* __restrict__ X, const float* __restrict__ Wo,
    const float* __restrict__ W1, const float* __restrict__ Wy,
    const float* __restrict__ by, const float* __restrict__ We,
    float* __restrict__ ws) {
  __shared__ float xs[2][C_];
  int row0 = blockIdx.x * 2;
  int t = threadIdx.x;
  if (t < 2*C_) xs[t >> 7][t & 127] = X[(size_t)row0*C_ + t];
  __syncthreads();

  int rsub = t >> 8;
  int col  = t & 255;
  int g = row0 + rsub;

  const float* W;
  if (col < 64)       W = Wo + (size_t)col*C_;
  else if (col < 128) W = W1 + (size_t)(col - 64)*C_;
  else                W = Wy + (size_t)(col - 128)*C_;

  const float4* w4 = (const float4*)W;
  const float4* x4 = (const float4*)xs[rsub];
  float acc = 0.f;
  #pragma unroll 8
  for (int k = 0; k < C_/4; ++k) {
    float4 wv = w4[k];
    float4 xv = x4[k];
    acc = fmaf(wv.x, xv.x, acc);
    acc = fmaf(wv.y, xv.y, acc);
    acc = fmaf(wv.z, xv.z, acc);
    acc = fmaf(wv.w, xv.w, acc);
  }

  if (col < 64) {
    ws[OFF_V + (size_t)g*A_ + col] = fexp2(SC2L * acc);
  } else if (col < 128) {
    int a = col - 64;
    float u = fexp2(SC2L * acc);
    ws[OFF_US + (size_t)g*A_ + a] = u;
    int b = g >> 9, n = g & (N_-1);
    ws[OFF_UQ + (((size_t)(b*16 + (a >> 2)))*N_ + n)*4 + (a & 3)] = u;
  } else {
    int h = col - 128;
    ws[OFF_XY + (size_t)g*H_ + h] = acc + by[h];
  }

  if (blockIdx.x == 0) {   // transpose We [H][A] -> [A][H]
    for (int k = t; k < A_*H_; k += 512) {
      int h = k >> 6, a = k & 63;
      ws[OFF_WET + a*H_ + h] = We[k];
    }
  }
}

// ---------------- kernel 2: attention main ----------------
// 512 blocks x 512 threads (8 waves), TI=2, 2 blocks/CU.
// tanh(ho+h1) = 1 - 2*rcp(v*u+1): 2 VALU + 1 rcp per element.
__global__ __launch_bounds__(512) void attn_kernel(
    const float* __restrict__ Wphi, const float* __restrict__ be,
    const float* __restrict__ ws, float* __restrict__ out) {
  __shared__ float pkv0[A_], pkv1[A_], pkw[A_];
  __shared__ float sc[TI][N_];        // unnormalized softmax p
  __shared__ float reds[TI][8];
  __shared__ float ebw[TI][8][A_];    // per-wave Σ p·rcp partials
  __shared__ float ebar[TI][A_];      // unnormalized ebar (l - 2Σ)
  __shared__ float p1s[TI][4][H_];    // part1 partials per j-quarter

  int t = threadIdx.x;
  int w = t >> 6, lane = t & 63;
  int blk = blockIdx.x;
  int b = blk >> 8;
  int i0 = (blk & 255) * TI;

  const float* vg  = ws + OFF_V  + (size_t)(b*N_ + i0)*A_;
  const float* us  = ws + OFF_US + (size_t)(b*N_)*A_;
  const float4* uq = (const float4*)(ws + OFF_UQ) + (size_t)b*16*N_;
  const float* xyg = ws + OFF_XY + (size_t)(b*N_)*H_;
  const float* wet = ws + OFF_WET;

  if (t < A_) {
    pkv0[t] = vg[t];
    pkv1[t] = vg[A_ + t];
    pkw[t]  = Wphi[t];
  }
  __syncthreads();

  // ---- Pass A: thread owns j = t.  s'_r = Σ_a wph_a·rcp(v_r·u + 1)
  float s0 = 0.f, s1 = 0.f;
  {
    #pragma unroll 4
    for (int a4 = 0; a4 < 16; ++a4) {
      float4 u  = uq[a4*N_ + t];
      float4 v0 = *(const float4*)&pkv0[a4*4];
      float4 v1 = *(const float4*)&pkv1[a4*4];
      float4 wq = *(const float4*)&pkw[a4*4];
      s0 = fmaf(wq.x, frcp(fmaf(v0.x, u.x, 1.f)), s0);
      s0 = fmaf(wq.y, frcp(fmaf(v0.y, u.y, 1.f)), s0);
      s0 = fmaf(wq.z, frcp(fmaf(v0.z, u.z, 1.f)), s0);
      s0 = fmaf(wq.w, frcp(fmaf(v0.w, u.w, 1.f)), s0);
      s1 = fmaf(wq.x, frcp(fmaf(v1.x, u.x, 1.f)), s1);
      s1 = fmaf(wq.y, frcp(fmaf(v1.y, u.y, 1.f)), s1);
      s1 = fmaf(wq.z, frcp(fmaf(v1.z, u.z, 1.f)), s1);
      s1 = fmaf(wq.w, frcp(fmaf(v1.w, u.w, 1.f)), s1);
    }
  }
  // score = Σwph - 2s'; softmax is shift-invariant -> p = exp(-2s') ; |s'| < 3
  float p0 = fexp2(NEG2LE * s0), p1 = fexp2(NEG2LE * s1);
  float q0 = p0, q1 = p1;
  #pragma unroll
  for (int m = 1; m < 64; m <<= 1) { q0 += __shfl_xor(q0, m); q1 += __shfl_xor(q1, m); }
  sc[0][t] = p0; sc[1][t] = p1;
  if (lane == 0) { reds[0][w] = q0; reds[1][w] = q1; }
  __syncthreads();
  float l0 = reds[0][0], l1 = reds[1][0];
  #pragma unroll
  for (int k = 1; k < 8; ++k) { l0 += reds[0][k]; l1 += reds[1][k]; }

  // ---- Pass C: lane = a, wave w covers j = jj*8+w.  c_r = Σ_j p_r·rcp(v_r·u+1)
  {
    float v0 = pkv0[lane], v1 = pkv1[lane];
    float c0 = 0.f, c1 = 0.f;
    #pragma unroll 8
    for (int jj = 0; jj < N_/8; ++jj) {
      int j = jj*8 + w;
      float u = us[(size_t)j*A_ + lane];
      float pj0 = sc[0][j], pj1 = sc[1][j];
      c0 = fmaf(pj0, frcp(fmaf(v0, u, 1.f)), c0);
      c1 = fmaf(pj1, frcp(fmaf(v1, u, 1.f)), c1);
    }
    ebw[0][w][lane] = c0; ebw[1][w][lane] = c1;
  }

  // ---- part1: thread = (qd = t>>7, h = t&127), 128 j each, rows share load
  {
    int h = t & 127, qd = t >> 7;
    const float* xq = xyg + (size_t)(qd*128)*H_ + h;
    float d0 = 0.f, d1 = 0.f;
    #pragma unroll 8
    for (int jc = 0; jc < 128; ++jc) {
      int j = qd*128 + jc;
      float xv = xq[(size_t)jc*H_];
      d0 = fmaf(sc[0][j], xv, d0);
      d1 = fmaf(sc[1][j], xv, d1);
    }
    p1s[0][qd][h] = d0; p1s[1][qd][h] = d1;
  }
  __syncthreads();

  // ---- combine ebar: ebar_un[r][a] = l_r - 2·Σ_w ebw[r][w][a]
  if (t < TI*A_) {
    int r = t >> 6, a = t & 63;
    float e = 0.f;
    #pragma unroll
    for (int k = 0; k < 8; ++k) e += ebw[r][k][a];
    ebar[r][a] = (r ? l1 : l0) - 2.0f*e;
  }
  __syncthreads();

  // ---- epilogue: out = (part1_un + We·ebar_un)·(1/l) + be
  if (t < TI*H_) {
    int h = t & 127, r = t >> 7;
    float acc = p1s[r][0][h] + p1s[r][1][h] + p1s[r][2][h] + p1s[r][3][h];
    float e2 = 0.f;
    #pragma unroll 8
    for (int a = 0; a < A_; ++a) e2 = fmaf(ebar[r][a], wet[a*H_ + h], e2);
    float l = r ? l1 : l0;
    out[(size_t)(b*N_ + i0 + r)*H_ + h] = (acc + e2) * frcp(l) + be[h];
  }
}

extern "C" void kernel_launch(void* const* d_in, const int* in_sizes, int n_in,
                              void* d_out, int out_size, void* d_ws, size_t ws_size,
                              hipStream_t stream) {
  const float* X    = (const float*)d_in[0];
  const float* Wo   = (const float*)d_in[1];
  const float* W1   = (const float*)d_in[2];
  const float* Wphi = (const float*)d_in[3];
  const float* Wy   = (const float*)d_in[4];
  const float* by   = (const float*)d_in[5];
  const float* We   = (const float*)d_in[6];
  const float* be   = (const float*)d_in[7];
  float* out = (float*)d_out;
  float* ws  = (float*)d_ws;

  hipLaunchKernelGGL(proj_kernel, dim3(B_*N_/2), dim3(512), 0, stream,
                     X, Wo, W1, Wy, by, We, ws);
  hipLaunchKernelGGL(attn_kernel, dim3(B_*N_/TI), dim3(512), 0, stream,
                     Wphi, be, ws, out);
}